// Round 12
// baseline (528.262 us; speedup 1.0000x reference)
//
#include <hip/hip_runtime.h>

#define T_SEQ 2048
#define NB 4
#define NH 16
#define HD 64
#define CDIM 1024
#define MROWS (NB * T_SEQ)  // 8192

typedef __attribute__((ext_vector_type(8))) short short8;
typedef __attribute__((ext_vector_type(4))) float floatx4;

static __device__ __forceinline__ unsigned short f2bf(float f) {
  union { float f; unsigned int i; } c; c.f = f;
  return (unsigned short)((c.i + 0x7FFFu + ((c.i >> 16) & 1u)) >> 16);
}
static __device__ __forceinline__ unsigned short f2bf_trunc(float f) {
  union { float f; unsigned int i; } c; c.f = f;
  return (unsigned short)(c.i >> 16);
}
static __device__ __forceinline__ void gl2lds16(const void* g, void* l) {
  __builtin_amdgcn_global_load_lds(
      (const __attribute__((address_space(1))) unsigned int*)g,
      (__attribute__((address_space(3))) unsigned int*)l, 16, 0, 0);
}

#define X4 (MROWS * CDIM / 4)            // 2097152
#define WQ4 (3 * CDIM * CDIM / 4)        // 786432
#define WP4 (CDIM * CDIM / 4)            // 262144
#define Q_PRESCALE 0.18033688f           // 1/sqrt(64) * log2(e)
#define PTP 72
#define SMEM_BYTES 51200                 // max(gemm 32K, attn 32K+18K)
#define NBLK 512

// Software grid barrier: monotonic counter, device scope. Safe because all
// 512 blocks are provably co-resident (launch_bounds(512,4): <=128 VGPR ->
// >=2 blocks/CU; LDS 51.2KB <= 80KB -> >=2 blocks/CU; 512 = 2*256).
static __device__ __forceinline__ void gsync(unsigned int* bar, unsigned int target) {
  __syncthreads();                      // all waves done (vmcnt drained by barrier)
  if (threadIdx.x == 0) {
    __threadfence();                    // prior global writes visible device-wide
    __hip_atomic_fetch_add(bar, 1u, __ATOMIC_ACQ_REL, __HIP_MEMORY_SCOPE_AGENT);
    while (__hip_atomic_load(bar, __ATOMIC_ACQUIRE, __HIP_MEMORY_SCOPE_AGENT) < target)
      __builtin_amdgcn_s_sleep(2);
    __threadfence();
  }
  __syncthreads();
}

// 8-wave 128x128 GEMM tile core: acc^T[mi<2][ni<4], dbuf DMA, 1 barrier/iter.
// Waves 0-3 stage A rows (w&3)*32..+31; waves 4-7 stage B rows likewise.
static __device__ __forceinline__ void gemm_core_8w(
    const unsigned short* __restrict__ A, const unsigned short* __restrict__ B,
    unsigned short* Asm, unsigned short* Bsm,
    int m0, int n0, int w, int l, floatx4 acc[2][4])
{
  const int quad = l >> 4, l15 = l & 15;
  const int srow = l >> 2;
  const int scol = ((l & 3) ^ (srow & 3)) * 8;    // XOR-swizzled source chunk
  const int sq = quad ^ (l15 & 3);                // swizzled read chunk
  const int wm = (w & 3) * 32, wn = (w >> 2) * 64;
  const int db = (w & 3) * 32 * 32;               // this wave's staging base

  const unsigned short* Sg = (w < 4)
      ? A + (size_t)(m0 + wm + srow) * CDIM + scol
      : B + (size_t)(n0 + (w & 3) * 32 + srow) * CDIM + scol;
  unsigned short* Lb = (w < 4) ? Asm : Bsm;

#pragma unroll
  for (int mi = 0; mi < 2; ++mi)
#pragma unroll
    for (int ni = 0; ni < 4; ++ni) acc[mi][ni] = (floatx4){0.f, 0.f, 0.f, 0.f};

  gl2lds16(Sg, Lb + db);                          // prologue: k0=0 -> buf0
  gl2lds16(Sg + 16 * CDIM, Lb + db + 512);

  for (int k0 = 0; k0 < CDIM; k0 += 32) {
    const int cur = (k0 >> 5) & 1, nxt = cur ^ 1;
    __syncthreads();                              // drains DMA; buf[cur] ready
    if (k0 + 32 < CDIM) {
      gl2lds16(Sg + k0 + 32, Lb + nxt * 4096 + db);
      gl2lds16(Sg + 16 * CDIM + k0 + 32, Lb + nxt * 4096 + db + 512);
    }
    short8 af[2], bf4[4];
#pragma unroll
    for (int mi = 0; mi < 2; ++mi)
      af[mi] = *(const short8*)&Asm[cur * 4096 + (wm + mi * 16 + l15) * 32 + sq * 8];
#pragma unroll
    for (int ni = 0; ni < 4; ++ni)
      bf4[ni] = *(const short8*)&Bsm[cur * 4096 + (wn + ni * 16 + l15) * 32 + sq * 8];
#pragma unroll
    for (int mi = 0; mi < 2; ++mi)
#pragma unroll
      for (int ni = 0; ni < 4; ++ni)              // swapped operands -> C^T
        acc[mi][ni] = __builtin_amdgcn_mfma_f32_16x16x32_bf16(bf4[ni], af[mi], acc[mi][ni], 0, 0, 0);
  }
  __syncthreads();                                // reads done before next prologue
}

__global__ __launch_bounds__(512, 4) void fused_all(
    const float* __restrict__ x, const float* __restrict__ Wq,
    const float* __restrict__ Wp, unsigned short* __restrict__ ws,
    float* __restrict__ out, unsigned int* __restrict__ bar)
{
  __shared__ __align__(16) unsigned char smem[SMEM_BYTES];
  const int tid = threadIdx.x;
  const int bid = blockIdx.x;
  const int w = tid >> 6, l = tid & 63;
  const int quad = l >> 4, l15 = l & 15;

  unsigned short* xb   = ws;
  unsigned short* wqb  = xb + (size_t)MROWS * CDIM;
  unsigned short* wpb  = wqb + (size_t)3 * CDIM * CDIM;
  unsigned short* qbuf = wpb + (size_t)CDIM * CDIM;
  unsigned short* kbuf = qbuf + (size_t)MROWS * CDIM;
  unsigned short* vtbuf = kbuf + (size_t)MROWS * CDIM;
  unsigned short* abuf = vtbuf + (size_t)MROWS * CDIM;

  // ============ phase 0: fused fp32->bf16 cast ============
  {
    const int total = X4 + WQ4 + WP4;
    for (int i = bid * 512 + tid; i < total; i += NBLK * 512) {
      const float* src; int off;
      if (i < X4) { src = x; off = i; }
      else if (i < X4 + WQ4) { src = Wq; off = i - X4; }
      else { src = Wp; off = i - X4 - WQ4; }
      const float4 v = ((const float4*)src)[off];
      ushort4 o;
      o.x = f2bf(v.x); o.y = f2bf(v.y); o.z = f2bf(v.z); o.w = f2bf(v.w);
      ((ushort4*)xb)[i] = o;
    }
  }
  gsync(bar, NBLK);

  // ============ phase 1: QKV GEMM (1536 tiles, 3 per block) ============
  {
    unsigned short* Asm = (unsigned short*)smem;    // [2][4096]
    unsigned short* Bsm = Asm + 8192;               // [2][4096]
#pragma unroll 1
    for (int it = 0; it < 3; ++it) {
      const int tile = bid + NBLK * it;             // 0..1535
      const int n0 = (tile / 64) * 128;             // 24 n-blocks
      const int m0 = (tile % 64) * 128;
      floatx4 acc[2][4];
      gemm_core_8w(xb, wqb, Asm, Bsm, m0, n0, w, l, acc);

      const int wm = (w & 3) * 32, wn = (w >> 2) * 64;
      const int which = n0 >> 10;                   // block-uniform
      if (which < 2) {
        unsigned short* dst = (which == 0) ? qbuf : kbuf;
        const float sc = (which == 0) ? Q_PRESCALE : 1.0f;
#pragma unroll
        for (int ni = 0; ni < 4; ++ni) {
          const int n = n0 + wn + ni * 16 + quad * 4;
          const int h = (n >> 6) & (NH - 1), d = n & (HD - 1);
#pragma unroll
          for (int mi = 0; mi < 2; ++mi) {
            const int m = m0 + wm + mi * 16 + l15;
            const int b = m >> 11, t = m & (T_SEQ - 1);
            ushort4 pk;
            pk.x = f2bf(acc[mi][ni][0] * sc); pk.y = f2bf(acc[mi][ni][1] * sc);
            pk.z = f2bf(acc[mi][ni][2] * sc); pk.w = f2bf(acc[mi][ni][3] * sc);
            *(ushort4*)(dst + (((size_t)(b * NH + h) * T_SEQ + t) << 6) + d) = pk;
          }
        }
      } else {
#pragma unroll
        for (int ni = 0; ni < 4; ++ni) {
          const int nb4 = n0 + wn + ni * 16 + quad * 4;
          const int h = (nb4 >> 6) & (NH - 1);
#pragma unroll
          for (int mi = 0; mi < 2; ++mi) {
            const int m = m0 + wm + mi * 16 + l15;
            const int b = m >> 11, t = m & (T_SEQ - 1);
#pragma unroll
            for (int r = 0; r < 4; ++r) {
              const int d = (nb4 + r) & (HD - 1);
              vtbuf[((size_t)((b * NH + h) * HD + d) << 11) + t] = f2bf(acc[mi][ni][r]);
            }
          }
        }
      }
    }
  }
  gsync(bar, 2 * NBLK);

  // ============ phase 2: flash attention (r10 v6, verified) ============
  {
    unsigned short* Ks  = (unsigned short*)smem;    // [2][4096] swizzled
    unsigned short* Vts = Ks + 8192;                // [2][4096] swizzled
    unsigned short* Pt  = Vts + 8192;               // [8][16*PTP]
    unsigned short* PtW = Pt + w * (16 * PTP);
    const int drow = 8 * w + (l >> 3);
    const int dch = ((l & 7) ^ (l >> 3)) * 8;
    const int sw7 = l15 & 7;

    const int bh = bid & 63;
    const int pp = bid >> 6;                        // 0..7
    const int b = bh >> 4, h = bh & 15;
    const size_t hoff = (size_t)bh * T_SEQ * HD;
    const unsigned short* Qh = qbuf + hoff;
    const unsigned short* Kdma = kbuf + hoff + (size_t)drow * HD + dch;
    const unsigned short* Vdma = vtbuf + hoff + ((size_t)drow << 11) + dch;
    const int wb = w * 512;

    short8 ones;
#pragma unroll
    for (int j = 0; j < 8; ++j) ones[j] = (short)0x3F80;

#pragma unroll 1
    for (int ii = 0; ii < 2; ++ii) {
      const int qtile = ii ? pp : (15 - pp);        // heavy first
      const int qw = qtile * 128 + w * 16;

      short8 qf[2];
      {
        const int qrow = qw + l15;
        qf[0] = *(const short8*)(Qh + (size_t)qrow * HD + quad * 8);
        qf[1] = *(const short8*)(Qh + (size_t)qrow * HD + 32 + quad * 8);
      }

      floatx4 Of[4];
#pragma unroll
      for (int dc = 0; dc < 4; ++dc) Of[dc] = (floatx4){0.f, 0.f, 0.f, 0.f};
      floatx4 lacc = (floatx4){0.f, 0.f, 0.f, 0.f};

      const int nkt = 2 * qtile + 2;
      gl2lds16(Kdma, &Ks[wb]);                      // prologue -> buf0
      gl2lds16(Vdma, &Vts[wb]);

      for (int kt = 0; kt < nkt; ++kt) {
        const int kt0 = kt * 64;
        const int cur = kt & 1, nxt = 1 - cur;
        __syncthreads();
        if (kt + 1 < nkt) {
          gl2lds16(Kdma + (size_t)(kt0 + 64) * HD, &Ks[nxt * 4096 + wb]);
          gl2lds16(Vdma + kt0 + 64, &Vts[nxt * 4096 + wb]);
        }

        if (qw + 15 >= kt0) {
          floatx4 Sf[4];
#pragma unroll
          for (int cb = 0; cb < 4; ++cb) {
            Sf[cb] = (floatx4){0.f, 0.f, 0.f, 0.f};
            const int krow = cb * 16 + l15;
#pragma unroll
            for (int h2 = 0; h2 < 2; ++h2) {
              const int ch = (h2 * 4 + quad) ^ sw7;
              const short8 kf = *(const short8*)&Ks[cur * 4096 + krow * 64 + ch * 8];
              Sf[cb] = __builtin_amdgcn_mfma_f32_16x16x32_bf16(kf, qf[h2], Sf[cb], 0, 0, 0);
            }
          }
          const bool full = (kt0 + 63 <= qw);
          const int q = qw + l15;
#pragma unroll
          for (int cb = 0; cb < 4; ++cb) {
            const int key0 = kt0 + cb * 16 + quad * 4;
            ushort4 pk;
            if (full) {
              pk.x = f2bf_trunc(exp2f(Sf[cb][0]));
              pk.y = f2bf_trunc(exp2f(Sf[cb][1]));
              pk.z = f2bf_trunc(exp2f(Sf[cb][2]));
              pk.w = f2bf_trunc(exp2f(Sf[cb][3]));
            } else {
              pk.x = (key0 + 0 > q) ? 0 : f2bf_trunc(exp2f(Sf[cb][0]));
              pk.y = (key0 + 1 > q) ? 0 : f2bf_trunc(exp2f(Sf[cb][1]));
              pk.z = (key0 + 2 > q) ? 0 : f2bf_trunc(exp2f(Sf[cb][2]));
              pk.w = (key0 + 3 > q) ? 0 : f2bf_trunc(exp2f(Sf[cb][3]));
            }
            *(ushort4*)&PtW[l15 * PTP + cb * 16 + quad * 4] = pk;
          }
#pragma unroll
          for (int kg = 0; kg < 2; ++kg) {
            const short8 ptf = *(const short8*)&PtW[l15 * PTP + kg * 32 + quad * 8];
            lacc = __builtin_amdgcn_mfma_f32_16x16x32_bf16(ones, ptf, lacc, 0, 0, 0);
#pragma unroll
            for (int dc = 0; dc < 4; ++dc) {
              const int vrow = dc * 16 + l15;
              const int ch = (kg * 4 + quad) ^ sw7;
              const short8 vf = *(const short8*)&Vts[cur * 4096 + vrow * 64 + ch * 8];
              Of[dc] = __builtin_amdgcn_mfma_f32_16x16x32_bf16(vf, ptf, Of[dc], 0, 0, 0);
            }
          }
        }
      }

      const float inv = 1.f / lacc[0];
      const int q = qw + l15;
      unsigned short* orow = abuf + (size_t)(b * T_SEQ + q) * CDIM + h * HD + quad * 4;
#pragma unroll
      for (int dc = 0; dc < 4; ++dc) {
        ushort4 ov;
        ov.x = f2bf(Of[dc][0] * inv); ov.y = f2bf(Of[dc][1] * inv);
        ov.z = f2bf(Of[dc][2] * inv); ov.w = f2bf(Of[dc][3] * inv);
        *(ushort4*)(orow + dc * 16) = ov;
      }
      __syncthreads();   // bufs safe before next ii's prologue
    }
  }
  gsync(bar, 3 * NBLK);

  // ============ phase 3: output projection (512 tiles, 1 per block) ============
  {
    unsigned short* Asm = (unsigned short*)smem;
    unsigned short* Bsm = Asm + 8192;
    const int n0 = (bid & 7) * 128, m0 = (bid >> 3) * 128;
    floatx4 acc[2][4];
    gemm_core_8w(abuf, wpb, Asm, Bsm, m0, n0, w, l, acc);

    const int wm = (w & 3) * 32, wn = (w >> 2) * 64;
#pragma unroll
    for (int ni = 0; ni < 4; ++ni) {
      const int n = n0 + wn + ni * 16 + quad * 4;
#pragma unroll
      for (int mi = 0; mi < 2; ++mi) {
        const int m = m0 + wm + mi * 16 + l15;
        *(float4*)(out + (size_t)m * CDIM + n) =
            make_float4(acc[mi][ni][0], acc[mi][ni][1], acc[mi][ni][2], acc[mi][ni][3]);
      }
    }
  }
}

extern "C" void kernel_launch(void* const* d_in, const int* in_sizes, int n_in,
                              void* d_out, int out_size, void* d_ws, size_t ws_size,
                              hipStream_t stream) {
  const float* x  = (const float*)d_in[0];   // [B,T,C]
  const float* Wq = (const float*)d_in[1];   // [3C,C]
  const float* Wp = (const float*)d_in[2];   // [C,C]
  float* out = (float*)d_out;                // [B,T,C] fp32
  unsigned short* ws = (unsigned short*)d_ws;

  // barrier counter lives after the last ws buffer (abuf end = 4*XSZ + ... )
  const size_t WSELEMS = (size_t)MROWS * CDIM * 5 + (size_t)4 * CDIM * CDIM;
  unsigned int* bar = (unsigned int*)(ws + WSELEMS);
  hipMemsetAsync(bar, 0, 64, stream);        // graph-capture-safe

  fused_all<<<NBLK, 512, 0, stream>>>(x, Wq, Wp, ws, out, bar);
}